// Round 1
// baseline (573.116 us; speedup 1.0000x reference)
//
#include <hip/hip_runtime.h>
#include <math.h>

#define LOG2E 1.4426950408889634f
#define LN2F  0.6931471805599453f

constexpr int M   = 2048;
constexpr int N   = 2048;
constexpr int D   = 256;
constexpr int MP1 = 2049;   // M+1 == N+1
constexpr int NCHUNK = 16;
constexpr int CHUNK  = (MP1 + NCHUNK - 1) / NCHUNK; // 129

__device__ inline float fast_exp2(float x) {
#if __has_builtin(__builtin_amdgcn_exp2f)
    return __builtin_amdgcn_exp2f(x);
#else
    return exp2f(x);
#endif
}
__device__ inline float fast_log2(float x) {
#if __has_builtin(__builtin_amdgcn_logf)
    return __builtin_amdgcn_logf(x);   // v_log_f32 is log2
#else
    return log2f(x);
#endif
}

struct TopLse { float t0, t1, t2, t3, t4, s; };

__device__ inline TopLse tl_init() {
    TopLse a;
    a.t0 = a.t1 = a.t2 = a.t3 = a.t4 = -INFINITY;
    a.s = 0.0f;
    return a;
}

// add element y: update top5 (sorted desc) + online base-2 lse state (m == t0)
__device__ inline void tl_add(TopLse& a, float y) {
    float m_old = a.t0;
    float m_new = fmaxf(m_old, y);
    // one of the exponents is exactly 0 -> exp2 == 1, so this is exact online lse
    a.s = a.s * fast_exp2(m_old - m_new) + fast_exp2(y - m_new);
    float v = y, mx;
    mx = fmaxf(a.t0, v); v = fminf(a.t0, v); a.t0 = mx;
    mx = fmaxf(a.t1, v); v = fminf(a.t1, v); a.t1 = mx;
    mx = fmaxf(a.t2, v); v = fminf(a.t2, v); a.t2 = mx;
    mx = fmaxf(a.t3, v); v = fminf(a.t3, v); a.t3 = mx;
    a.t4 = fmaxf(a.t4, v);
}

// merged[k] = max(a_k, b_k, max_{i+j=k-1} min(a_i,b_j)) for sorted-desc 5-lists
__device__ inline TopLse tl_merge(const TopLse& a, const TopLse& b) {
    TopLse r;
    r.t0 = fmaxf(a.t0, b.t0);
    r.t1 = fmaxf(fmaxf(a.t1, b.t1), fminf(a.t0, b.t0));
    r.t2 = fmaxf(fmaxf(a.t2, b.t2), fmaxf(fminf(a.t1, b.t0), fminf(a.t0, b.t1)));
    r.t3 = fmaxf(fmaxf(a.t3, b.t3),
           fmaxf(fmaxf(fminf(a.t2, b.t0), fminf(a.t1, b.t1)), fminf(a.t0, b.t2)));
    r.t4 = fmaxf(fmaxf(a.t4, b.t4),
           fmaxf(fmaxf(fminf(a.t3, b.t0), fminf(a.t2, b.t1)),
                 fmaxf(fminf(a.t1, b.t2), fminf(a.t0, b.t3))));
    r.s = a.s * fast_exp2(a.t0 - r.t0) + b.s * fast_exp2(b.t0 - r.t0);
    return r;
}

__device__ inline TopLse tl_shfl_xor(const TopLse& a, int off) {
    TopLse o;
    o.t0 = __shfl_xor(a.t0, off, 64);
    o.t1 = __shfl_xor(a.t1, off, 64);
    o.t2 = __shfl_xor(a.t2, off, 64);
    o.t3 = __shfl_xor(a.t3, off, 64);
    o.t4 = __shfl_xor(a.t4, off, 64);
    o.s  = __shfl_xor(a.s , off, 64);
    return o;
}

__device__ inline float gelu_exact(float x) {
    return 0.5f * x * (1.0f + erff(x * 0.70710678118654752f));
}

// ---------------------------------------------------------------------------
// dA[b,m,p] = sum_d mdesc[b,d,m] * pw[p,d] + pb[p];  dustbin row m==M -> 0
// grid (9, B, 2), block 256
// ---------------------------------------------------------------------------
__global__ __launch_bounds__(256) void proj_kernel(
    const float* __restrict__ mdesc0, const float* __restrict__ mdesc1,
    const float* __restrict__ pA_w, const float* __restrict__ pA_b,
    const float* __restrict__ pB_w, const float* __restrict__ pB_b,
    float* __restrict__ dA, float* __restrict__ dB)
{
    const int which = blockIdx.z;
    const float* mdesc = which ? mdesc1 : mdesc0;
    const float* pw    = which ? pB_w : pA_w;
    const float* pb    = which ? pB_b : pA_b;
    float* dOut        = which ? dB   : dA;

    __shared__ float swT[D * 8];   // transposed: swT[d*8+p]
    const int tid = threadIdx.x;
    for (int idx = tid; idx < 8 * D; idx += 256) {
        int p = idx >> 8, d = idx & (D - 1);
        swT[d * 8 + p] = pw[idx];
    }
    __syncthreads();

    const int m = blockIdx.x * 256 + tid;
    const int b = blockIdx.y;
    if (m > M) return;
    float* out = dOut + ((size_t)b * MP1 + m) * 8;
    if (m == M) {
        #pragma unroll
        for (int p = 0; p < 8; ++p) out[p] = 0.0f;
        return;
    }
    float acc[8];
    #pragma unroll
    for (int p = 0; p < 8; ++p) acc[p] = pb[p];
    const float* base = mdesc + (size_t)b * D * M + m;
    #pragma unroll 4
    for (int d = 0; d < D; ++d) {
        float x = base[(size_t)d * M];
        #pragma unroll
        for (int p = 0; p < 8; ++p) acc[p] = fmaf(x, swT[d * 8 + p], acc[p]);
    }
    #pragma unroll
    for (int p = 0; p < 8; ++p) out[p] = acc[p];
}

// ---------------------------------------------------------------------------
// Row pass: per (b,r): reduce over c of y = S[r,c] + v[c]; write u_new + feats
// grid (2049, B), block 256.  first_iter: v treated as all-zero.
// ---------------------------------------------------------------------------
__global__ __launch_bounds__(256) void row_pass(
    const float* __restrict__ scores, const float* __restrict__ alpha,
    const float* __restrict__ v, const float* __restrict__ dA,
    float* __restrict__ u, float* __restrict__ featR, int first_iter)
{
    const int r = blockIdx.x;
    const int b = blockIdx.y;
    const int tid = threadIdx.x;
    const float alpha2 = alpha[0] * LOG2E;
    const float* vb = v + b * MP1;

    TopLse st = tl_init();
    if (r < M) {
        const float* srow = scores + ((size_t)b * M + r) * N;
        if (first_iter) {
            #pragma unroll
            for (int k = 0; k < 8; ++k) {
                int c = tid + 256 * k;
                tl_add(st, srow[c] * LOG2E);
            }
            if (tid == 0) tl_add(st, alpha2);
        } else {
            #pragma unroll
            for (int k = 0; k < 8; ++k) {
                int c = tid + 256 * k;
                tl_add(st, fmaf(srow[c], LOG2E, vb[c]));
            }
            if (tid == 0) tl_add(st, alpha2 + vb[N]);
        }
    } else {
        if (first_iter) {
            #pragma unroll
            for (int k = 0; k < 8; ++k) tl_add(st, alpha2);
            if (tid == 0) tl_add(st, alpha2);
        } else {
            #pragma unroll
            for (int k = 0; k < 8; ++k) {
                int c = tid + 256 * k;
                tl_add(st, alpha2 + vb[c]);
            }
            if (tid == 0) tl_add(st, alpha2 + vb[N]);
        }
    }
    // wave butterfly merge
    #pragma unroll
    for (int off = 32; off >= 1; off >>= 1) {
        TopLse o = tl_shfl_xor(st, off);
        st = tl_merge(st, o);
    }
    __shared__ float sred[4][8];
    if ((tid & 63) == 0) {
        int w = tid >> 6;
        sred[w][0] = st.t0; sred[w][1] = st.t1; sred[w][2] = st.t2;
        sred[w][3] = st.t3; sred[w][4] = st.t4; sred[w][5] = st.s;
    }
    __syncthreads();
    if (tid == 0) {
        TopLse a;
        a.t0 = sred[0][0]; a.t1 = sred[0][1]; a.t2 = sred[0][2];
        a.t3 = sred[0][3]; a.t4 = sred[0][4]; a.s = sred[0][5];
        #pragma unroll
        for (int w = 1; w < 4; ++w) {
            TopLse o;
            o.t0 = sred[w][0]; o.t1 = sred[w][1]; o.t2 = sred[w][2];
            o.t3 = sred[w][3]; o.t4 = sred[w][4]; o.s = sred[w][5];
            a = tl_merge(a, o);
        }
        float lse = a.t0 + fast_log2(a.s);
        float l2w = (r < M) ? -12.0f : -1.0f;   // norm=-log2(4096); log2(N)+norm
        float un  = l2w - lse;
        int i = b * MP1 + r;
        u[i] = un;
        float* f = featR + (size_t)i * 16;
        f[0] = l2w * LN2F;
        f[1] = un  * LN2F;
        f[2] = 0.0f;
        f[3] = (a.t0 - a.t1) * LN2F;
        f[4] = (a.t0 - a.t2) * LN2F;
        f[5] = (a.t0 - a.t3) * LN2F;
        f[6] = (a.t0 - a.t4) * LN2F;
        f[7] = (lse - a.t0) * LN2F;
        const float* d = dA + (size_t)i * 8;
        #pragma unroll
        for (int p = 0; p < 8; ++p) f[8 + p] = d[p];
    }
}

// ---------------------------------------------------------------------------
// Col pass: chunked over rows. grid (9, NCHUNK, B), block 256.
// Each thread owns one column, reduces rows [chunk*CHUNK, ...) of y=S[r,c]+u[r]
// ---------------------------------------------------------------------------
__global__ __launch_bounds__(256) void col_pass(
    const float* __restrict__ scores, const float* __restrict__ alpha,
    const float* __restrict__ u, float* __restrict__ partial)
{
    const int c = blockIdx.x * 256 + threadIdx.x;
    const int chunk = blockIdx.y;
    const int b = blockIdx.z;
    const int r0 = chunk * CHUNK;
    const int r1 = min(r0 + CHUNK, MP1);

    __shared__ float su[CHUNK];
    const float* ub = u + b * MP1;
    for (int i = threadIdx.x; i < r1 - r0; i += 256) su[i] = ub[r0 + i];
    __syncthreads();
    if (c > N) return;

    const float alpha2 = alpha[0] * LOG2E;
    TopLse st = tl_init();
    if (c < N) {
        const float* sc = scores + (size_t)b * M * N + c;
        for (int r = r0; r < r1; ++r) {
            float base = (r < M) ? sc[(size_t)r * N] * LOG2E : alpha2;
            tl_add(st, base + su[r - r0]);
        }
    } else {
        for (int r = r0; r < r1; ++r) tl_add(st, alpha2 + su[r - r0]);
    }
    float* p = partial + ((size_t)(b * NCHUNK + chunk) * MP1 + c) * 6;
    p[0] = st.t0; p[1] = st.t1; p[2] = st.t2; p[3] = st.t3; p[4] = st.t4; p[5] = st.s;
}

// grid (9, B), block 256: merge NCHUNK partials per column, write v_new + feats
__global__ __launch_bounds__(256) void col_combine(
    const float* __restrict__ partial, const float* __restrict__ dB,
    float* __restrict__ v, float* __restrict__ featC)
{
    const int c = blockIdx.x * 256 + threadIdx.x;
    const int b = blockIdx.y;
    if (c > N) return;
    const float* p0 = partial + ((size_t)(b * NCHUNK + 0) * MP1 + c) * 6;
    TopLse a;
    a.t0 = p0[0]; a.t1 = p0[1]; a.t2 = p0[2]; a.t3 = p0[3]; a.t4 = p0[4]; a.s = p0[5];
    for (int k = 1; k < NCHUNK; ++k) {
        const float* p = partial + ((size_t)(b * NCHUNK + k) * MP1 + c) * 6;
        TopLse o;
        o.t0 = p[0]; o.t1 = p[1]; o.t2 = p[2]; o.t3 = p[3]; o.t4 = p[4]; o.s = p[5];
        a = tl_merge(a, o);
    }
    float lse = a.t0 + fast_log2(a.s);
    float l2w = (c < N) ? -12.0f : -1.0f;
    float vn  = l2w - lse;
    int i = b * MP1 + c;
    v[i] = vn;
    float* f = featC + (size_t)i * 16;
    f[0] = l2w * LN2F;
    f[1] = vn  * LN2F;
    f[2] = 0.0f;
    f[3] = (a.t0 - a.t1) * LN2F;
    f[4] = (a.t0 - a.t2) * LN2F;
    f[5] = (a.t0 - a.t3) * LN2F;
    f[6] = (a.t0 - a.t4) * LN2F;
    f[7] = (lse - a.t0) * LN2F;
    const float* d = dB + (size_t)i * 8;
    #pragma unroll
    for (int p = 0; p < 8; ++p) f[8 + p] = d[p];
}

// ---------------------------------------------------------------------------
// MLP: 16 -> 64 gelu LN -> 64 gelu LN -> 1; dual[i] += out * LOG2E
// grid (B*2049), block 64 (one wave; lane = hidden unit)
// ---------------------------------------------------------------------------
__device__ inline float wave_sum(float x) {
    #pragma unroll
    for (int off = 32; off >= 1; off >>= 1) x += __shfl_xor(x, off, 64);
    return x;
}

__global__ __launch_bounds__(64) void mlp_kernel(
    const float* __restrict__ feats, float* __restrict__ dual,
    const float* __restrict__ w1, const float* __restrict__ b1,
    const float* __restrict__ g1, const float* __restrict__ be1,
    const float* __restrict__ w2, const float* __restrict__ b2,
    const float* __restrict__ g2, const float* __restrict__ be2,
    const float* __restrict__ w3, const float* __restrict__ b3)
{
    const int i = blockIdx.x;
    const int j = threadIdx.x;
    __shared__ float shF[16];
    __shared__ float shH[64];
    if (j < 16) shF[j] = feats[(size_t)i * 16 + j];
    __syncthreads();
    float h = b1[j];
    #pragma unroll
    for (int k = 0; k < 16; ++k) h = fmaf(shF[k], w1[j * 16 + k], h);
    h = gelu_exact(h);
    float mu  = wave_sum(h) * (1.0f / 64.0f);
    float d   = h - mu;
    float var = wave_sum(d * d) * (1.0f / 64.0f);
    float hn  = d * rsqrtf(var + 1e-5f) * g1[j] + be1[j];
    shH[j] = hn;
    __syncthreads();
    float h2 = b2[j];
    #pragma unroll
    for (int k = 0; k < 64; ++k) h2 = fmaf(shH[k], w2[j * 64 + k], h2);
    h2 = gelu_exact(h2);
    mu  = wave_sum(h2) * (1.0f / 64.0f);
    d   = h2 - mu;
    var = wave_sum(d * d) * (1.0f / 64.0f);
    hn  = d * rsqrtf(var + 1e-5f) * g2[j] + be2[j];
    float o = wave_sum(hn * w3[j]);
    if (j == 0) dual[i] += (o + b3[0]) * LOG2E;
}

// ---------------------------------------------------------------------------
// out[b,r,c] = S + u[b,r] + v[b,c] - norm   (norm = -12)
// grid (9, 2049, B), block 256
// ---------------------------------------------------------------------------
__global__ __launch_bounds__(256) void final_kernel(
    const float* __restrict__ scores, const float* __restrict__ alpha,
    const float* __restrict__ u, const float* __restrict__ v,
    float* __restrict__ out)
{
    const int c = blockIdx.x * 256 + threadIdx.x;
    const int r = blockIdx.y;
    const int b = blockIdx.z;
    if (c > N) return;
    const float alpha2 = alpha[0] * LOG2E;
    float S = (r < M && c < N) ? scores[((size_t)b * M + r) * N + c] * LOG2E : alpha2;
    out[((size_t)b * MP1 + r) * MP1 + c] = S + u[b * MP1 + r] + v[b * MP1 + c] + 12.0f;
}

extern "C" void kernel_launch(void* const* d_in, const int* in_sizes, int n_in,
                              void* d_out, int out_size, void* d_ws, size_t ws_size,
                              hipStream_t stream) {
    const float* scores = (const float*)d_in[0];
    const float* alpha  = (const float*)d_in[1];
    const float* mdesc0 = (const float*)d_in[2];
    const float* mdesc1 = (const float*)d_in[3];
    const float* pA_w = (const float*)d_in[4];
    const float* pA_b = (const float*)d_in[5];
    const float* pB_w = (const float*)d_in[6];
    const float* pB_b = (const float*)d_in[7];
    const float* rW[10]; const float* cW[10];
    for (int k = 0; k < 10; ++k) rW[k] = (const float*)d_in[8 + k];
    for (int k = 0; k < 10; ++k) cW[k] = (const float*)d_in[18 + k];
    float* out = (float*)d_out;

    const int B = in_sizes[0] / (M * N);

    float* ws = (float*)d_ws;
    float* u     = ws;                       // B*MP1
    float* v     = u + (size_t)B * MP1;      // B*MP1
    float* dA    = v + (size_t)B * MP1;      // B*MP1*8
    float* dB    = dA + (size_t)B * MP1 * 8; // B*MP1*8
    float* featR = dB + (size_t)B * MP1 * 8; // B*MP1*16
    float* featC = featR + (size_t)B * MP1 * 16;
    float* partial = featC + (size_t)B * MP1 * 16; // B*NCHUNK*MP1*6

    const int CB = (MP1 + 255) / 256; // 9

    proj_kernel<<<dim3(CB, B, 2), 256, 0, stream>>>(
        mdesc0, mdesc1, pA_w, pA_b, pB_w, pB_b, dA, dB);

    for (int it = 0; it < 3; ++it) {
        row_pass<<<dim3(MP1, B), 256, 0, stream>>>(
            scores, alpha, v, dA, u, featR, it == 0 ? 1 : 0);
        mlp_kernel<<<dim3(B * MP1), 64, 0, stream>>>(
            featR, u, rW[0], rW[1], rW[2], rW[3], rW[4], rW[5], rW[6], rW[7], rW[8], rW[9]);
        col_pass<<<dim3(CB, NCHUNK, B), 256, 0, stream>>>(scores, alpha, u, partial);
        col_combine<<<dim3(CB, B), 256, 0, stream>>>(partial, dB, v, featC);
        mlp_kernel<<<dim3(B * MP1), 64, 0, stream>>>(
            featC, v, cW[0], cW[1], cW[2], cW[3], cW[4], cW[5], cW[6], cW[7], cW[8], cW[9]);
    }
    final_kernel<<<dim3(CB, MP1, B), 256, 0, stream>>>(scores, alpha, u, v, out);
}

// Round 2
// 388.598 us; speedup vs baseline: 1.4748x; 1.4748x over previous
//
#include <hip/hip_runtime.h>
#include <math.h>

#define LOG2E 1.4426950408889634f
#define LN2F  0.6931471805599453f

constexpr int M   = 2048;
constexpr int N   = 2048;
constexpr int D   = 256;
constexpr int MP1 = 2049;   // M+1 == N+1
constexpr int NCHUNK = 32;
constexpr int CHUNK  = 64;  // NCHUNK*CHUNK == 2048 score rows; dustbin row added in combine

__device__ inline float fast_exp2(float x) {
#if __has_builtin(__builtin_amdgcn_exp2f)
    return __builtin_amdgcn_exp2f(x);
#else
    return exp2f(x);
#endif
}
__device__ inline float fast_log2(float x) {
#if __has_builtin(__builtin_amdgcn_logf)
    return __builtin_amdgcn_logf(x);   // v_log_f32 is log2
#else
    return log2f(x);
#endif
}
// NaN-guarded exp2 for identity (-inf) merges: fmaxf(NaN,-2e4) = -2e4 -> exp2 -> 0
__device__ inline float exp2g(float x) { return fast_exp2(fmaxf(x, -20000.0f)); }

__device__ inline void insert5(float t[5], float y) {
    float v = y, mx;
    #pragma unroll
    for (int k = 0; k < 5; ++k) { mx = fmaxf(t[k], v); v = fminf(t[k], v); t[k] = mx; }
}

// merge sorted-desc top5 lists + lse states: merged[k]=max(a_k,b_k,max_{i+j=k-1}min(a_i,b_j))
__device__ inline void merge5(float a[5], float& as, const float b[5], float bs) {
    float r0 = fmaxf(a[0], b[0]);
    float r1 = fmaxf(fmaxf(a[1], b[1]), fminf(a[0], b[0]));
    float r2 = fmaxf(fmaxf(a[2], b[2]), fmaxf(fminf(a[1], b[0]), fminf(a[0], b[1])));
    float r3 = fmaxf(fmaxf(a[3], b[3]),
               fmaxf(fmaxf(fminf(a[2], b[0]), fminf(a[1], b[1])), fminf(a[0], b[2])));
    float r4 = fmaxf(fmaxf(a[4], b[4]),
               fmaxf(fmaxf(fminf(a[3], b[0]), fminf(a[2], b[1])),
                     fmaxf(fminf(a[1], b[2]), fminf(a[0], b[3]))));
    as = as * exp2g(a[0] - r0) + bs * exp2g(b[0] - r0);
    a[0] = r0; a[1] = r1; a[2] = r2; a[3] = r3; a[4] = r4;
}

__device__ inline void merge5_shfl_xor(float t[5], float& s, int off) {
    float b[5], bs;
    #pragma unroll
    for (int k = 0; k < 5; ++k) b[k] = __shfl_xor(t[k], off, 64);
    bs = __shfl_xor(s, off, 64);
    merge5(t, s, b, bs);
}

// online add of one element to (t,s) state; t[0] must be finite or y finite
__device__ inline void online_add(float t[5], float& s, float y) {
    float m_old = t[0];
    float m_new = fmaxf(m_old, y);
    s = s * exp2g(m_old - m_new) + fast_exp2(y - m_new);
    insert5(t, y);
}

__device__ inline float gelu_exact(float x) {
    return 0.5f * x * (1.0f + erff(x * 0.70710678118654752f));
}

__device__ inline float wave_sum(float x) {
    #pragma unroll
    for (int off = 32; off >= 1; off >>= 1) x += __shfl_xor(x, off, 64);
    return x;
}

// one-wave MLP: 16 -> 64 gelu LN -> 64 gelu LN -> 1. f[] is lane-uniform, j = lane.
// returns wave-uniform scalar output.
__device__ inline float mlp_wave(const float f[16], int j,
    const float* __restrict__ w1, const float* __restrict__ b1,
    const float* __restrict__ g1, const float* __restrict__ be1,
    const float* __restrict__ w2, const float* __restrict__ b2,
    const float* __restrict__ g2, const float* __restrict__ be2,
    const float* __restrict__ w3, const float* __restrict__ b3)
{
    float h = b1[j];
    #pragma unroll
    for (int k = 0; k < 16; ++k) h = fmaf(f[k], w1[j * 16 + k], h);
    h = gelu_exact(h);
    float mu  = wave_sum(h) * (1.0f / 64.0f);
    float d   = h - mu;
    float var = wave_sum(d * d) * (1.0f / 64.0f);
    float hn  = d * rsqrtf(var + 1e-5f) * g1[j] + be1[j];
    float h2 = b2[j];
    #pragma unroll
    for (int k = 0; k < 64; ++k) h2 = fmaf(__shfl(hn, k, 64), w2[j * 64 + k], h2);
    h2 = gelu_exact(h2);
    mu  = wave_sum(h2) * (1.0f / 64.0f);
    d   = h2 - mu;
    var = wave_sum(d * d) * (1.0f / 64.0f);
    float hn2 = d * rsqrtf(var + 1e-5f) * g2[j] + be2[j];
    return wave_sum(hn2 * w3[j]) + b3[0];
}

// ---------------------------------------------------------------------------
// dA[b,m,p] = sum_d mdesc[b,d,m] * pw[p,d] + pb[p];  dustbin row m==M -> 0
// grid (9, B, 2), block 256
// ---------------------------------------------------------------------------
__global__ __launch_bounds__(256) void proj_kernel(
    const float* __restrict__ mdesc0, const float* __restrict__ mdesc1,
    const float* __restrict__ pA_w, const float* __restrict__ pA_b,
    const float* __restrict__ pB_w, const float* __restrict__ pB_b,
    float* __restrict__ dA, float* __restrict__ dB)
{
    const int which = blockIdx.z;
    const float* mdesc = which ? mdesc1 : mdesc0;
    const float* pw    = which ? pB_w : pA_w;
    const float* pb    = which ? pB_b : pA_b;
    float* dOut        = which ? dB   : dA;

    __shared__ float swT[D * 8];   // transposed: swT[d*8+p]
    const int tid = threadIdx.x;
    for (int idx = tid; idx < 8 * D; idx += 256) {
        int p = idx >> 8, d = idx & (D - 1);
        swT[d * 8 + p] = pw[idx];
    }
    __syncthreads();

    const int m = blockIdx.x * 256 + tid;
    const int b = blockIdx.y;
    if (m > M) return;
    float* out = dOut + ((size_t)b * MP1 + m) * 8;
    if (m == M) {
        #pragma unroll
        for (int p = 0; p < 8; ++p) out[p] = 0.0f;
        return;
    }
    float acc[8];
    #pragma unroll
    for (int p = 0; p < 8; ++p) acc[p] = pb[p];
    const float* base = mdesc + (size_t)b * D * M + m;
    #pragma unroll 4
    for (int d = 0; d < D; ++d) {
        float x = base[(size_t)d * M];
        #pragma unroll
        for (int p = 0; p < 8; ++p) acc[p] = fmaf(x, swT[d * 8 + p], acc[p]);
    }
    #pragma unroll
    for (int p = 0; p < 8; ++p) out[p] = acc[p];
}

// ---------------------------------------------------------------------------
// Row pass + fused MLP. grid (2049, B), block 256.
// Reduces y = S[r,:]*LOG2E + v over columns, computes feats, wave0 runs MLP,
// writes u[b,r] = u_pre + mlp_out*LOG2E.
// ---------------------------------------------------------------------------
__global__ __launch_bounds__(256) void row_fused(
    const float* __restrict__ scores, const float* __restrict__ alpha,
    const float* __restrict__ v, const float* __restrict__ dA,
    float* __restrict__ u, int first_iter,
    const float* __restrict__ w1, const float* __restrict__ b1,
    const float* __restrict__ g1, const float* __restrict__ be1,
    const float* __restrict__ w2, const float* __restrict__ b2,
    const float* __restrict__ g2, const float* __restrict__ be2,
    const float* __restrict__ w3, const float* __restrict__ b3)
{
    const int r = blockIdx.x;
    const int b = blockIdx.y;
    const int tid = threadIdx.x;
    const float alpha2 = alpha[0] * LOG2E;
    const float* vb = v + b * MP1;

    // batched loads -> y[8]
    float y[8];
    float extra = 0.0f;
    if (r < M) {
        const float* srow = scores + ((size_t)b * M + r) * N;
        if (first_iter) {
            #pragma unroll
            for (int k = 0; k < 8; ++k) y[k] = srow[tid + 256 * k] * LOG2E;
            extra = alpha2;
        } else {
            #pragma unroll
            for (int k = 0; k < 8; ++k) {
                int c = tid + 256 * k;
                y[k] = fmaf(srow[c], LOG2E, vb[c]);
            }
            extra = alpha2 + vb[N];
        }
    } else {
        if (first_iter) {
            #pragma unroll
            for (int k = 0; k < 8; ++k) y[k] = alpha2;
            extra = alpha2;
        } else {
            #pragma unroll
            for (int k = 0; k < 8; ++k) y[k] = alpha2 + vb[tid + 256 * k];
            extra = alpha2 + vb[N];
        }
    }

    // per-thread top5 (no exp2 in the chain), then independent exp2 sum
    float t[5];
    #pragma unroll
    for (int k = 0; k < 5; ++k) t[k] = -INFINITY;
    #pragma unroll
    for (int k = 0; k < 8; ++k) insert5(t, y[k]);
    float s = 0.0f;
    #pragma unroll
    for (int k = 0; k < 8; ++k) s += fast_exp2(y[k] - t[0]);
    if (tid == 0) online_add(t, s, extra);   // dustbin column element

    // wave butterfly merge
    #pragma unroll
    for (int off = 32; off >= 1; off >>= 1) merge5_shfl_xor(t, s, off);

    __shared__ float sred[4][8];
    if ((tid & 63) == 0) {
        int w = tid >> 6;
        #pragma unroll
        for (int k = 0; k < 5; ++k) sred[w][k] = t[k];
        sred[w][5] = s;
    }
    __syncthreads();
    if (tid >= 64) return;   // waves 1-3 done; no further block barriers

    // wave 0: merge the 4 wave-partials (replicated on all 64 lanes)
    float a[5], as;
    #pragma unroll
    for (int k = 0; k < 5; ++k) a[k] = sred[0][k];
    as = sred[0][5];
    #pragma unroll
    for (int w = 1; w < 4; ++w) {
        float bt[5];
        #pragma unroll
        for (int k = 0; k < 5; ++k) bt[k] = sred[w][k];
        merge5(a, as, bt, sred[w][5]);
    }

    float lse = a[0] + fast_log2(as);
    float l2w = (r < M) ? -12.0f : -1.0f;   // norm=-log2(4096); log2(N)+norm
    float un  = l2w - lse;
    const int i = b * MP1 + r;

    float f[16];
    f[0] = l2w * LN2F;
    f[1] = un  * LN2F;
    f[2] = 0.0f;
    f[3] = (a[0] - a[1]) * LN2F;
    f[4] = (a[0] - a[2]) * LN2F;
    f[5] = (a[0] - a[3]) * LN2F;
    f[6] = (a[0] - a[4]) * LN2F;
    f[7] = (lse - a[0]) * LN2F;
    const float* dd = dA + (size_t)i * 8;
    #pragma unroll
    for (int p = 0; p < 8; ++p) f[8 + p] = dd[p];

    float o = mlp_wave(f, tid, w1, b1, g1, be1, w2, b2, g2, be2, w3, b3);
    if (tid == 0) u[i] = un + o * LOG2E;
}

// ---------------------------------------------------------------------------
// Col pass: grid (9, NCHUNK, B), block 256. Thread owns column c, reduces its
// CHUNK=64 rows register-resident (64 outstanding loads), writes partial.
// Rows covered: [0, 2048). Dustbin row handled in col_mlp_fused.
// partial layout: [b][chunk][c][8]  (write-coalesced, float4-aligned)
// ---------------------------------------------------------------------------
__global__ __launch_bounds__(256) void col_pass(
    const float* __restrict__ scores, const float* __restrict__ alpha,
    const float* __restrict__ u, float* __restrict__ partial)
{
    const int tid = threadIdx.x;
    const int chunk = blockIdx.y;
    const int b = blockIdx.z;
    const int r0 = chunk * CHUNK;

    __shared__ float su[CHUNK];
    if (tid < CHUNK) su[tid] = u[b * MP1 + r0 + tid];
    __syncthreads();

    const int c = blockIdx.x * 256 + tid;
    if (c > N) return;

    const float alpha2 = alpha[0] * LOG2E;
    float y[CHUNK];
    if (c < N) {
        const float* base = scores + (size_t)b * M * N + (size_t)r0 * N + c;
        #pragma unroll
        for (int i = 0; i < CHUNK; ++i) y[i] = fmaf(base[(size_t)i * N], LOG2E, su[i]);
    } else {
        #pragma unroll
        for (int i = 0; i < CHUNK; ++i) y[i] = alpha2 + su[i];
    }

    float t[5];
    #pragma unroll
    for (int k = 0; k < 5; ++k) t[k] = -INFINITY;
    #pragma unroll
    for (int i = 0; i < CHUNK; ++i) insert5(t, y[i]);
    float s = 0.0f;
    #pragma unroll
    for (int i = 0; i < CHUNK; ++i) s += fast_exp2(y[i] - t[0]);

    float4* p4 = (float4*)(partial + (((size_t)(b * NCHUNK + chunk) * MP1) + c) * 8);
    p4[0] = make_float4(t[0], t[1], t[2], t[3]);
    p4[1] = make_float4(t[4], s, 0.0f, 0.0f);
}

// ---------------------------------------------------------------------------
// Col combine + fused MLP: grid (2049, B), block 64 (one wave).
// lane k<NCHUNK loads partial k; butterfly merge (NaN-guarded for identity
// lanes); add dustbin row; feats; MLP; write v.
// ---------------------------------------------------------------------------
__global__ __launch_bounds__(64) void col_mlp_fused(
    const float* __restrict__ partial, const float* __restrict__ dB,
    const float* __restrict__ u, const float* __restrict__ alpha,
    float* __restrict__ v,
    const float* __restrict__ w1, const float* __restrict__ b1,
    const float* __restrict__ g1, const float* __restrict__ be1,
    const float* __restrict__ w2, const float* __restrict__ b2,
    const float* __restrict__ g2, const float* __restrict__ be2,
    const float* __restrict__ w3, const float* __restrict__ b3)
{
    const int c = blockIdx.x;
    const int b = blockIdx.y;
    const int lane = threadIdx.x;
    const float alpha2 = alpha[0] * LOG2E;

    float t[5], s;
    if (lane < NCHUNK) {
        const float4* p4 = (const float4*)(partial + (((size_t)(b * NCHUNK + lane) * MP1) + c) * 8);
        float4 A = p4[0], Bv = p4[1];
        t[0] = A.x; t[1] = A.y; t[2] = A.z; t[3] = A.w; t[4] = Bv.x; s = Bv.y;
    } else {
        #pragma unroll
        for (int k = 0; k < 5; ++k) t[k] = -INFINITY;
        s = 0.0f;
    }
    #pragma unroll
    for (int off = 32; off >= 1; off >>= 1) merge5_shfl_xor(t, s, off);

    // dustbin row r==M: value alpha2 + u[M] for every column (incl. c==N)
    online_add(t, s, alpha2 + u[b * MP1 + M]);

    float lse = t[0] + fast_log2(s);
    float l2w = (c < N) ? -12.0f : -1.0f;
    float vn  = l2w - lse;
    const int i = b * MP1 + c;

    float f[16];
    f[0] = l2w * LN2F;
    f[1] = vn  * LN2F;
    f[2] = 0.0f;
    f[3] = (t[0] - t[1]) * LN2F;
    f[4] = (t[0] - t[2]) * LN2F;
    f[5] = (t[0] - t[3]) * LN2F;
    f[6] = (t[0] - t[4]) * LN2F;
    f[7] = (lse - t[0]) * LN2F;
    const float* dd = dB + (size_t)i * 8;
    #pragma unroll
    for (int p = 0; p < 8; ++p) f[8 + p] = dd[p];

    float o = mlp_wave(f, lane, w1, b1, g1, be1, w2, b2, g2, be2, w3, b3);
    if (lane == 0) v[i] = vn + o * LOG2E;
}

// ---------------------------------------------------------------------------
// out[b,r,c] = S*LOG2E + u[b,r] + v[b,c] + 12.  grid (2049, B), block 256.
// ---------------------------------------------------------------------------
__global__ __launch_bounds__(256) void final_kernel(
    const float* __restrict__ scores, const float* __restrict__ alpha,
    const float* __restrict__ u, const float* __restrict__ v,
    float* __restrict__ out)
{
    const int r = blockIdx.x;
    const int b = blockIdx.y;
    const int tid = threadIdx.x;
    const float alpha2 = alpha[0] * LOG2E;
    const float* vb = v + b * MP1;
    const float ur = u[b * MP1 + r] + 12.0f;
    float* orow = out + ((size_t)b * MP1 + r) * MP1;

    if (r < M) {
        const float* srow = scores + ((size_t)b * M + r) * N;
        #pragma unroll
        for (int k = 0; k < 8; ++k) {
            int c = tid + 256 * k;
            orow[c] = fmaf(srow[c], LOG2E, ur + vb[c]);
        }
    } else {
        #pragma unroll
        for (int k = 0; k < 8; ++k) {
            int c = tid + 256 * k;
            orow[c] = alpha2 + ur + vb[c];
        }
    }
    if (tid == 0) orow[N] = alpha2 + ur + vb[N];
}

extern "C" void kernel_launch(void* const* d_in, const int* in_sizes, int n_in,
                              void* d_out, int out_size, void* d_ws, size_t ws_size,
                              hipStream_t stream) {
    const float* scores = (const float*)d_in[0];
    const float* alpha  = (const float*)d_in[1];
    const float* mdesc0 = (const float*)d_in[2];
    const float* mdesc1 = (const float*)d_in[3];
    const float* pA_w = (const float*)d_in[4];
    const float* pA_b = (const float*)d_in[5];
    const float* pB_w = (const float*)d_in[6];
    const float* pB_b = (const float*)d_in[7];
    const float* rW[10]; const float* cW[10];
    for (int k = 0; k < 10; ++k) rW[k] = (const float*)d_in[8 + k];
    for (int k = 0; k < 10; ++k) cW[k] = (const float*)d_in[18 + k];
    float* out = (float*)d_out;

    const int B = in_sizes[0] / (M * N);

    float* ws = (float*)d_ws;
    float* u       = ws;                        // B*MP1
    float* v       = u + (size_t)B * MP1;       // B*MP1
    float* dA      = v + (size_t)B * MP1;       // B*MP1*8
    float* dB      = dA + (size_t)B * MP1 * 8;  // B*MP1*8
    float* partial = dB + (size_t)B * MP1 * 8;  // B*NCHUNK*MP1*8

    const int CB = (MP1 + 255) / 256; // 9

    proj_kernel<<<dim3(CB, B, 2), 256, 0, stream>>>(
        mdesc0, mdesc1, pA_w, pA_b, pB_w, pB_b, dA, dB);

    for (int it = 0; it < 3; ++it) {
        row_fused<<<dim3(MP1, B), 256, 0, stream>>>(
            scores, alpha, v, dA, u, it == 0 ? 1 : 0,
            rW[0], rW[1], rW[2], rW[3], rW[4], rW[5], rW[6], rW[7], rW[8], rW[9]);
        col_pass<<<dim3(CB, NCHUNK, B), 256, 0, stream>>>(scores, alpha, u, partial);
        col_mlp_fused<<<dim3(MP1, B), 64, 0, stream>>>(
            partial, dB, u, alpha, v,
            cW[0], cW[1], cW[2], cW[3], cW[4], cW[5], cW[6], cW[7], cW[8], cW[9]);
    }
    final_kernel<<<dim3(MP1, B), 256, 0, stream>>>(scores, alpha, u, v, out);
}